// Round 1
// 435.129 us; speedup vs baseline: 1.2574x; 1.2574x over previous
//
#include <hip/hip_runtime.h>
#include <hip/hip_bf16.h>

// Problem constants (B=8, L=8192, C=256, PE=96, R=90, UP=4, OUT=256)
#define M_TOTAL 65536   // B*L
#define N_TOTAL 1024    // OUT*UP
#define K_TOTAL 448     // C + 2*PE
#define R_PE    90

typedef __bf16 bf16x8 __attribute__((ext_vector_type(8)));
typedef __bf16 bf16x4 __attribute__((ext_vector_type(4)));
typedef float  floatx4 __attribute__((ext_vector_type(4)));

// ---------------------------------------------------------------------------
// async global->LDS, 16B per lane. LDS dest = wave-uniform base + lane*16.
// ---------------------------------------------------------------------------
__device__ __forceinline__ void g2lds16(const void* g, void* l) {
    __builtin_amdgcn_global_load_lds(
        (const __attribute__((address_space(1))) void*)g,
        (__attribute__((address_space(3))) void*)l,
        16, 0, 0);
}

// ---------------------------------------------------------------------------
// cpe [3][96][90] -> cpeT [3][90][96] so the per-row d-gather is coalesced.
// ---------------------------------------------------------------------------
__global__ __launch_bounds__(256) void transpose_cpe(
    const float* __restrict__ cpe, float* __restrict__ cpeT)
{
    int i = blockIdx.x * 256 + threadIdx.x;
    if (i < 3 * 96 * R_PE) {
        int c = i / (96 * R_PE);
        int rem = i % (96 * R_PE);
        int d = rem / R_PE;
        int r = rem % R_PE;
        cpeT[((size_t)c * R_PE + r) * 96 + d] = cpe[i];
    }
}

// ---------------------------------------------------------------------------
// Stage 1: x_pe[m, 0:448] = [bf16(x[m]), sin(LFF(pc[m])), constPE(pc[m])]
// One row per WAVE: pc is lane-uniform (broadcast), X copy is 64xfloat4,
// LFF weights hoisted (loop-invariant per lane), cpeT gathers coalesced.
// ---------------------------------------------------------------------------
__global__ __launch_bounds__(256) void build_xpe(
    const float* __restrict__ X,      // [65536, 256]
    const float* __restrict__ pc,     // [65536, 3]
    const float* __restrict__ lff_w,  // [96, 3]
    const float* __restrict__ lff_b,  // [96]
    const float* __restrict__ cpeT,   // [3, 90, 96] (transposed)
    __bf16* __restrict__ xpe)         // [65536, 448]
{
    const int wave = threadIdx.x >> 6;
    const int lane = threadIdx.x & 63;

    // hoisted LFF params: slot0 d=lane (all), slot1 d=64+lane (lane<32)
    const float w00 = lff_w[lane * 3 + 0];
    const float w01 = lff_w[lane * 3 + 1];
    const float w02 = lff_w[lane * 3 + 2];
    const float bb0 = lff_b[lane];
    float w10 = 0.f, w11 = 0.f, w12 = 0.f, bb1 = 0.f;
    if (lane < 32) {
        w10 = lff_w[(64 + lane) * 3 + 0];
        w11 = lff_w[(64 + lane) * 3 + 1];
        w12 = lff_w[(64 + lane) * 3 + 2];
        bb1 = lff_b[64 + lane];
    }

    for (int m = blockIdx.x * 4 + wave; m < M_TOTAL; m += gridDim.x * 4) {
        const float p0 = pc[m * 3 + 0];   // lane-uniform -> broadcast
        const float p1 = pc[m * 3 + 1];
        const float p2 = pc[m * 3 + 2];
        __bf16* row = xpe + (size_t)m * K_TOTAL;

        // ---- x copy: 64 lanes x float4 = full 1KB row, coalesced ----
        float4 v = ((const float4*)(X + (size_t)m * 256))[lane];
        bf16x4 xo = { (__bf16)v.x, (__bf16)v.y, (__bf16)v.z, (__bf16)v.w };
        *(bf16x4*)(row + lane * 4) = xo;

        // ---- lpe: sin(pc . w + b) ----
        float a0 = fmaf(p2, w02, fmaf(p1, w01, fmaf(p0, w00, bb0)));
        row[256 + lane] = (__bf16)__sinf(a0);
        if (lane < 32) {
            float a1 = fmaf(p2, w12, fmaf(p1, w11, fmaf(p0, w10, bb1)));
            row[256 + 64 + lane] = (__bf16)__sinf(a1);
        }

        // ---- cpe: bilinear over transposed table, coalesced in d ----
        const float pch[3] = { p0, p1, p2 };
        const float* tab0[3];
        const float* tab1[3];
        float m0[3], m1[3];
        #pragma unroll
        for (int c = 0; c < 3; ++c) {
            float ix = (pch[c] + 1.f) * 45.f - 0.5f;   // ((p+1)*R-1)*0.5
            float fl = floorf(ix);
            float w  = ix - fl;
            int   i0 = (int)fl;
            bool  ok0 = (i0 >= 0) && (i0 < R_PE);
            bool  ok1 = (i0 + 1 >= 0) && (i0 + 1 < R_PE);
            int   c0 = ok0 ? i0 : 0;
            int   c1 = ok1 ? i0 + 1 : 0;
            tab0[c] = cpeT + ((size_t)c * R_PE + c0) * 96;
            tab1[c] = cpeT + ((size_t)c * R_PE + c1) * 96;
            m0[c] = ok0 ? (1.f - w) : 0.f;
            m1[c] = ok1 ? w : 0.f;
        }
        float acc0 = 0.f;
        #pragma unroll
        for (int c = 0; c < 3; ++c)
            acc0 += m0[c] * tab0[c][lane] + m1[c] * tab1[c][lane];
        row[352 + lane] = (__bf16)(acc0 * 0.57735026918962576f);  // 1/sqrt(3)
        if (lane < 32) {
            float acc1 = 0.f;
            #pragma unroll
            for (int c = 0; c < 3; ++c)
                acc1 += m0[c] * tab0[c][64 + lane] + m1[c] * tab1[c][64 + lane];
            row[352 + 64 + lane] = (__bf16)(acc1 * 0.57735026918962576f);
        }
    }
}

// ---------------------------------------------------------------------------
// sub_w [1024,448] f32 -> bf16 (already B^T layout: N-major, K-contiguous)
// ---------------------------------------------------------------------------
__global__ __launch_bounds__(256) void convert_w(
    const float* __restrict__ w, __bf16* __restrict__ wb)
{
    int i = (blockIdx.x * 256 + threadIdx.x) * 4;
    if (i < N_TOTAL * K_TOTAL) {
        float4 v = *(const float4*)(w + i);
        bf16x4 o = { (__bf16)v.x, (__bf16)v.y, (__bf16)v.z, (__bf16)v.w };
        *(bf16x4*)(wb + i) = o;
    }
}

// ---------------------------------------------------------------------------
// pc_up: repeat_interleave(pc, 4, axis=1)
// ---------------------------------------------------------------------------
__global__ __launch_bounds__(256) void pc_up_kernel(
    const float* __restrict__ pc, float* __restrict__ out2)
{
    int e = blockIdx.x * 256 + threadIdx.x;
    if (e < M_TOTAL * 12) {
        int m = e / 12;
        int j = e % 3;
        out2[e] = pc[m * 3 + j];
    }
}

// ---------------------------------------------------------------------------
// GEMM: C[m,n] = sum_k xpe[m,k] * sub_w[n,k], fused subpixel epilogue.
// 128x128 tile, BK=64, 4 waves. Changes vs prior version:
//  - double-buffered LDS + T3-min pipeline: issue next tile's global_load_lds
//    BEFORE ds_read+MFMA of current tile; single vmcnt(0)+barrier per K-step.
//  - LDS XOR swizzle (chunk ^= row&7) applied on the *global source* side
//    (global_load_lds writes linearly) + same involution on ds_read -> kills
//    the 16-way bank conflict on 128B-stride rows.
// ---------------------------------------------------------------------------
__global__ __launch_bounds__(256) void gemm_kernel(
    const __bf16* __restrict__ A,    // [65536, 448] bf16 (x_pe)
    const __bf16* __restrict__ Bw,   // [1024, 448] bf16 (sub_w^T-major)
    const float* __restrict__ bias,  // [1024]
    const float* __restrict__ X,     // [65536, 256] f32 residual
    float* __restrict__ out)         // x_up part of d_out
{
    __shared__ __bf16 As[2][128 * 64];  // 2 x 16 KB
    __shared__ __bf16 Bs[2][128 * 64];  // 2 x 16 KB

    const int tid  = threadIdx.x;
    const int wave = tid >> 6;
    const int lane = tid & 63;
    const int quad = lane >> 4;
    const int l16  = lane & 15;
    const int wm   = (wave >> 1) * 64;
    const int wn   = (wave & 1) * 64;

    // XCD-aware swizzle (bijective, grid=4096): all 8 N-blocks of one M-tile
    // land on the same XCD for A-tile / residual-X L2 reuse.
    const unsigned bx = blockIdx.x;
    const int bm = (int)(((bx & 7u) * 64u + (bx >> 6)) * 128u);
    const int bn = (int)(((bx >> 3) & 7u) * 128u);

    const __bf16* Arow = A  + (size_t)bm * K_TOTAL;
    const __bf16* Brow = Bw + (size_t)bn * K_TOTAL;

    floatx4 acc[4][4];
    #pragma unroll
    for (int i = 0; i < 4; ++i)
        #pragma unroll
        for (int j = 0; j < 4; ++j)
            acc[i][j] = (floatx4){0.f, 0.f, 0.f, 0.f};

    auto stage = [&](int buf, int kt) {
        #pragma unroll
        for (int s = 0; s < 4; ++s) {
            const int idx = s * 256 + tid;          // 16B chunk id, [0,1024)
            const int r   = idx >> 3;               // tile row
            const int cs  = (idx & 7) ^ (r & 7);    // pre-swizzled source chunk
            __bf16* la = &As[buf][(size_t)(s * 256 + wave * 64) * 8];
            __bf16* lb = &Bs[buf][(size_t)(s * 256 + wave * 64) * 8];
            g2lds16(Arow + (size_t)r * K_TOTAL + kt + cs * 8, la);
            g2lds16(Brow + (size_t)r * K_TOTAL + kt + cs * 8, lb);
        }
    };

    // prologue: stage tile 0, drain, barrier
    stage(0, 0);
    asm volatile("s_waitcnt vmcnt(0)" ::: "memory");
    __builtin_amdgcn_s_barrier();

    #pragma unroll
    for (int t = 0; t < 7; ++t) {
        const int cur = t & 1;
        if (t < 6) stage(cur ^ 1, (t + 1) * 64);    // issue next-tile loads

        const __bf16* Ac = &As[cur][0];
        const __bf16* Bc = &Bs[cur][0];
        #pragma unroll
        for (int s = 0; s < 2; ++s) {
            bf16x8 af[4], bfr[4];
            #pragma unroll
            for (int i = 0; i < 4; ++i) {
                const int row = wm + i * 16 + l16;
                const int ch  = (s * 4 + quad) ^ (row & 7);   // read-side swizzle
                af[i] = *(const bf16x8*)(Ac + row * 64 + ch * 8);
            }
            #pragma unroll
            for (int j = 0; j < 4; ++j) {
                const int row = wn + j * 16 + l16;
                const int ch  = (s * 4 + quad) ^ (row & 7);
                bfr[j] = *(const bf16x8*)(Bc + row * 64 + ch * 8);
            }
            __builtin_amdgcn_s_setprio(1);
            #pragma unroll
            for (int i = 0; i < 4; ++i)
                #pragma unroll
                for (int j = 0; j < 4; ++j)
                    acc[i][j] = __builtin_amdgcn_mfma_f32_16x16x32_bf16(
                        af[i], bfr[j], acc[i][j], 0, 0, 0);
            __builtin_amdgcn_s_setprio(0);
        }
        // drain this wave's LDS reads AND the prefetch writes, then barrier:
        // next iter overwrites buf cur, reads buf cur^1.
        asm volatile("s_waitcnt vmcnt(0) lgkmcnt(0)" ::: "memory");
        __builtin_amdgcn_s_barrier();
    }

    // ---- fused epilogue ----
    const float gain = 0.047245559126153576f;     // 1/sqrt(448)
    const float inv_sqrt2 = 0.70710678118654752f;
    #pragma unroll
    for (int i = 0; i < 4; ++i) {
        #pragma unroll
        for (int j = 0; j < 4; ++j) {
            const int n = bn + wn + j * 16 + l16;
            const float bs = bias[n];
            const int o = n & 255;
            const int u = n >> 8;
            #pragma unroll
            for (int r = 0; r < 4; ++r) {
                const int m = bm + wm + i * 16 + quad * 4 + r;
                float y = acc[i][j][r] * gain + bs;
                float act = (y >= 0.f) ? y : 0.2f * y;   // lrelu*sqrt2 /sqrt2 == 1
                float res = X[(size_t)m * 256 + o];
                out[((size_t)(m * 4 + u)) * 256 + o] = fmaf(res, inv_sqrt2, act);
            }
        }
    }
}

// ---------------------------------------------------------------------------
extern "C" void kernel_launch(void* const* d_in, const int* in_sizes, int n_in,
                              void* d_out, int out_size, void* d_ws, size_t ws_size,
                              hipStream_t stream) {
    const float* X      = (const float*)d_in[0];  // [8,8192,256]
    const float* pc     = (const float*)d_in[1];  // [8,8192,3]
    const float* lff_w  = (const float*)d_in[2];  // [96,3]
    const float* lff_b  = (const float*)d_in[3];  // [96]
    const float* cpe    = (const float*)d_in[4];  // [3,96,90]
    const float* sub_w  = (const float*)d_in[5];  // [1024,448]
    const float* sub_b  = (const float*)d_in[6];  // [1024]

    float* out    = (float*)d_out;                       // x_up: 67108864 floats
    float* out_pc = out + (size_t)M_TOTAL * 4 * 256;     // pc_up: 786432 floats

    // workspace: x_pe bf16 [65536,448], sub_w bf16 [1024,448], cpeT f32 [3,90,96]
    __bf16* xpe  = (__bf16*)d_ws;
    __bf16* wb   = (__bf16*)((char*)d_ws + (size_t)M_TOTAL * K_TOTAL * 2);
    float*  cpeT = (float*)((char*)d_ws + (size_t)M_TOTAL * K_TOTAL * 2
                                        + (size_t)N_TOTAL * K_TOTAL * 2);

    convert_w    <<<448,  256, 0, stream>>>(sub_w, wb);
    pc_up_kernel <<<3072, 256, 0, stream>>>(pc, out_pc);
    transpose_cpe<<<102,  256, 0, stream>>>(cpe, cpeT);
    build_xpe    <<<4096, 256, 0, stream>>>(X, pc, lff_w, lff_b, cpeT, xpe);
    gemm_kernel  <<<4096, 256, 0, stream>>>(xpe, wb, sub_b, X, out);
}